// Round 3
// baseline (266.536 us; speedup 1.0000x reference)
//
#include <hip/hip_runtime.h>

// Problem constants
#define BTOT   32768
#define NNODE  78
#define NEMB   30
#define NPROJ  10
#define NGR    7
#define ROW    (NNODE*NEMB)   // 2340 floats per batch row
#define BT     4              // batches per workgroup
#define FEAT_OUT (BTOT*NGR*NEMB)  // 6881280

__constant__ int d_off[NGR] = {0,5,14,23,48,57,66};
__constant__ int d_len[NGR] = {5,9,9,25,9,9,12};
__constant__ signed char d_gid[NNODE] = {
  0,0,0,0,0,
  1,1,1,1,1,1,1,1,1,
  2,2,2,2,2,2,2,2,2,
  3,3,3,3,3,3,3,3,3,3,3,3,3,3,3,3,3,3,3,3,3,3,3,3,3,
  4,4,4,4,4,4,4,4,4,
  5,5,5,5,5,5,5,5,5,
  6,6,6,6,6,6,6,6,6,6,6,6
};

__global__ __launch_bounds__(256) void meso_main(
    const float* __restrict__ x, const float* __restrict__ wt,
    float* __restrict__ out, float* __restrict__ attsum)
{
  __shared__ __align__(16) float xs[BT*ROW];     // 9360 floats = 37.4 KB
  __shared__ float wls[NEMB*NPROJ];              // 300
  __shared__ float Ms[NEMB*NEMB];                // 900 : M = W W^T
  __shared__ float xsum_s[BT*NGR*NEMB];          // 840
  __shared__ float v_s[BT*NGR*NEMB];             // 840
  __shared__ float att_s[BT*NNODE];              // 312

  const int tid = threadIdx.x;
  const long long b0 = (long long)blockIdx.x * BT;

  // ---- Phase 0: stage x tile (contiguous 37440 B) + weight ----
  {
    const float4* src = (const float4*)(x + b0 * ROW);
    float4* dst = (float4*)xs;
    #pragma unroll
    for (int k = 0; k < (BT*ROW/4 + 255)/256; ++k) {
      int i = tid + k*256;
      if (i < BT*ROW/4) dst[i] = src[i];
    }
    for (int i = tid; i < NEMB*NPROJ; i += 256)  // FIXED: 300 > 256, was if(tid<300)
      wls[i] = wt[i];
  }
  __syncthreads();

  // ---- Phase 1: M = W W^T (900 jobs) ----
  for (int i = tid; i < NEMB*NEMB; i += 256) {
    int a = i / NEMB, c = i % NEMB;
    float s = 0.f;
    #pragma unroll
    for (int h = 0; h < NPROJ; ++h) s += wls[a*NPROJ+h]*wls[c*NPROJ+h];
    Ms[i] = s;
  }
  __syncthreads();

  // ---- Phase 2: per-(b,graph) emb-sum of sub_f (840 jobs) ----
  for (int i = tid; i < BT*NGR*NEMB; i += 256) {
    int b = i / (NGR*NEMB), r = i % (NGR*NEMB), g = r / NEMB, e = r % NEMB;
    int off = d_off[g], len = d_len[g];
    const float* p = xs + b*ROW + off*NEMB + e;
    float s = 0.f;
    for (int j = 0; j < len; ++j) s += p[j*NEMB];
    xsum_s[i] = s;
  }
  __syncthreads();

  // ---- Phase 3: v = M * xsum (840 jobs) ----
  for (int i = tid; i < BT*NGR*NEMB; i += 256) {
    int e = i % NEMB;
    int base = i - e;
    float s = 0.f;
    #pragma unroll
    for (int a = 0; a < NEMB; ++a) s += Ms[e*NEMB+a]*xsum_s[base+a];
    v_s[i] = s;
  }
  __syncthreads();

  // ---- Phase 4: logits[b,n] = sub_f[b,n,:] . v[b,g(n),:] (312 jobs, strided) ----
  for (int i = tid; i < BT*NNODE; i += 256) {
    int b = i / NNODE, n = i % NNODE;
    int g = d_gid[n];
    const float* xr = xs + b*ROW + n*NEMB;
    const float* vr = v_s + (b*NGR+g)*NEMB;
    float s = 0.f;
    #pragma unroll
    for (int e = 0; e < NEMB; ++e) s += xr[e]*vr[e];
    att_s[i] = s;
  }
  __syncthreads();

  // ---- Phase 5: softmax per (b,graph) (28 jobs) ----
  if (tid < BT*NGR) {
    int b = tid / NGR, g = tid % NGR;
    int off = d_off[g], len = d_len[g];
    float* a = att_s + b*NNODE + off;
    float m = a[0];
    for (int j = 1; j < len; ++j) m = fmaxf(m, a[j]);
    float s = 0.f;
    for (int j = 0; j < len; ++j) { float e_ = __expf(a[j]-m); a[j] = e_; s += e_; }
    float inv = 1.f / s;
    for (int j = 0; j < len; ++j) a[j] *= inv;
  }
  __syncthreads();

  // ---- Phase 6: feat[b,g,e] = sum_j att*sub_f; contiguous 840-float store ----
  for (int i = tid; i < BT*NGR*NEMB; i += 256) {
    int b = i / (NGR*NEMB), r = i % (NGR*NEMB), g = r / NEMB, e = r % NEMB;
    int off = d_off[g], len = d_len[g];
    const float* xp = xs + b*ROW + off*NEMB + e;
    const float* ap = att_s + b*NNODE + off;
    float s = 0.f;
    for (int j = 0; j < len; ++j) s += ap[j]*xp[j*NEMB];
    out[(size_t)(b0 + b)*(NGR*NEMB) + (size_t)g*NEMB + e] = s;
  }

  // ---- Phase 7: attention partial sums -> global atomics (78 jobs) ----
  if (tid < NNODE) {
    float s = 0.f;
    #pragma unroll
    for (int b = 0; b < BT; ++b) s += att_s[b*NNODE + tid];
    atomicAdd(&attsum[tid], s);
  }
}

__global__ void meso_coor(const float* __restrict__ attsum,
                          const float* __restrict__ coords,
                          float* __restrict__ out_coor)
{
  int t = threadIdx.x;
  if (t < NGR*3) {
    int g = t / 3, k = t % 3;
    int off = d_off[g], len = d_len[g];
    float s = 0.f;
    for (int j = 0; j < len; ++j) s += attsum[off+j] * coords[(off+j)*3 + k];
    out_coor[t] = s * (1.0f/(float)BTOT);
  }
}

extern "C" void kernel_launch(void* const* d_in, const int* in_sizes, int n_in,
                              void* d_out, int out_size, void* d_ws, size_t ws_size,
                              hipStream_t stream) {
  const float* x      = (const float*)d_in[0];
  const float* coords = (const float*)d_in[1];
  const float* wt     = (const float*)d_in[2];
  float* out    = (float*)d_out;
  float* attsum = (float*)d_ws;

  hipMemsetAsync(attsum, 0, NNODE*sizeof(float), stream);
  meso_main<<<BTOT/BT, 256, 0, stream>>>(x, wt, out, attsum);
  meso_coor<<<1, 64, 0, stream>>>(attsum, coords, out + FEAT_OUT);
}

// Round 4
// 166.730 us; speedup vs baseline: 1.5986x; 1.5986x over previous
//
#include <hip/hip_runtime.h>
#include <math.h>

#define BTOT   32768
#define NNODE  78
#define NEMB   30
#define NPROJ  10
#define NGR    7
#define ROW    (NNODE*NEMB)       // 2340 floats per batch
#define BPW    8                  // batches per WG = 8 half-waves (256 threads)
#define FEAT_OUT (BTOT*NGR*NEMB)

__constant__ int d_off[NGR] = {0,5,14,23,48,57,66};
__constant__ int d_len[NGR] = {5,9,9,25,9,9,12};

// One 32-lane group processes one (batch, graph). Lane = embedding dim e.
// All loops compile-time → registers statically indexed, fully unrolled.
template<int OFF, int LEN, int G>
__device__ __forceinline__ void process_graph(
    const float* __restrict__ xrow,   // x + b*ROW
    const float* __restrict__ Ms,     // LDS: M = W W^T (symmetric, 30x30)
    float* __restrict__ arow,         // LDS: this half-wave's att row (78)
    float* __restrict__ outb,         // out + b*210
    int lane31, bool evalid, int e)
{
  // Stream sub-block into registers (x read exactly once from HBM), xsum on the fly.
  float xr[LEN];
  float xsum = 0.f;
#pragma unroll
  for (int j = 0; j < LEN; ++j) {
    float v = xrow[(OFF + j) * NEMB + e];  // 120B contiguous per j across lanes
    v = evalid ? v : 0.f;                  // lanes 30,31 contribute zeros
    xr[j] = v;
    xsum += v;
  }
  // u[e] = sum_a M[a][e] * xsum[a]  (M symmetric -> row-read is conflict-free)
  float u = 0.f;
#pragma unroll
  for (int a = 0; a < NEMB; ++a) {
    float xa = __shfl(xsum, a, 32);
    u = fmaf(Ms[a * NEMB + e], xa, u);
  }
  // logit[j] = sum_e x[j,e]*u[e] : butterfly reduce, keep own logit in lane j
  float mylog = -INFINITY;
#pragma unroll
  for (int j = 0; j < LEN; ++j) {
    float t = xr[j] * u;                   // zero in invalid lanes
    t += __shfl_xor(t, 1, 32);
    t += __shfl_xor(t, 2, 32);
    t += __shfl_xor(t, 4, 32);
    t += __shfl_xor(t, 8, 32);
    t += __shfl_xor(t, 16, 32);
    if (lane31 == j) mylog = t;            // cndmask
  }
  // softmax across lanes 0..LEN-1 (others hold -inf -> p=0)
  float m = mylog;
  m = fmaxf(m, __shfl_xor(m, 1, 32));
  m = fmaxf(m, __shfl_xor(m, 2, 32));
  m = fmaxf(m, __shfl_xor(m, 4, 32));
  m = fmaxf(m, __shfl_xor(m, 8, 32));
  m = fmaxf(m, __shfl_xor(m, 16, 32));
  float p = (lane31 < LEN) ? __expf(mylog - m) : 0.f;
  float s = p;
  s += __shfl_xor(s, 1, 32);
  s += __shfl_xor(s, 2, 32);
  s += __shfl_xor(s, 4, 32);
  s += __shfl_xor(s, 8, 32);
  s += __shfl_xor(s, 16, 32);
  float att = p / s;
  if (lane31 < LEN) arow[OFF + lane31] = att;   // for cross-batch attsum
  // feat[e] = sum_j att[j] * x[j,e]
  float f = 0.f;
#pragma unroll
  for (int j = 0; j < LEN; ++j)
    f = fmaf(__shfl(att, j, 32), xr[j], f);
  if (evalid) outb[G * NEMB + e] = f;           // 120B contiguous store
}

__global__ __launch_bounds__(256) void meso_main(
    const float* __restrict__ x, const float* __restrict__ wt,
    float* __restrict__ out, float* __restrict__ attsum)
{
  __shared__ float Wls[NEMB*NPROJ];        // 300 floats
  __shared__ float Ms[NEMB*NEMB];          // 900 floats: M = W W^T
  __shared__ float att_all[BPW][NNODE];    // 8 x 78

  const int tid = threadIdx.x;

  // Build M = W W^T once per WG (trivial: 9000 FLOP)
  for (int i = tid; i < NEMB*NPROJ; i += 256) Wls[i] = wt[i];
  __syncthreads();
  for (int i = tid; i < NEMB*NEMB; i += 256) {
    int a = i / NEMB, c = i % NEMB;
    float s = 0.f;
#pragma unroll
    for (int h = 0; h < NPROJ; ++h) s += Wls[a*NPROJ+h]*Wls[c*NPROJ+h];
    Ms[i] = s;
  }
  __syncthreads();

  const int half   = tid >> 5;       // 0..7 : batch slot
  const int lane31 = tid & 31;
  const bool evalid = lane31 < NEMB;
  const int e = evalid ? lane31 : (NEMB - 1);   // clamp, contributions zeroed

  const long long b = (long long)blockIdx.x * BPW + half;
  const float* xrow = x + b * ROW;
  float* outb = out + b * (NGR * NEMB);
  float* arow = att_all[half];

  process_graph< 0, 5,0>(xrow, Ms, arow, outb, lane31, evalid, e);
  process_graph< 5, 9,1>(xrow, Ms, arow, outb, lane31, evalid, e);
  process_graph<14, 9,2>(xrow, Ms, arow, outb, lane31, evalid, e);
  process_graph<23,25,3>(xrow, Ms, arow, outb, lane31, evalid, e);
  process_graph<48, 9,4>(xrow, Ms, arow, outb, lane31, evalid, e);
  process_graph<57, 9,5>(xrow, Ms, arow, outb, lane31, evalid, e);
  process_graph<66,12,6>(xrow, Ms, arow, outb, lane31, evalid, e);

  // Cross-batch attention sum: per-WG LDS reduce, then one atomic per node.
  __syncthreads();
  if (tid < NNODE) {
    float s = 0.f;
#pragma unroll
    for (int h = 0; h < BPW; ++h) s += att_all[h][tid];
    atomicAdd(&attsum[tid], s);
  }
}

__global__ void meso_coor(const float* __restrict__ attsum,
                          const float* __restrict__ coords,
                          float* __restrict__ out_coor)
{
  int t = threadIdx.x;
  if (t < NGR*3) {
    int g = t / 3, k = t % 3;
    int off = d_off[g], len = d_len[g];
    float s = 0.f;
    for (int j = 0; j < len; ++j) s += attsum[off+j] * coords[(off+j)*3 + k];
    out_coor[t] = s * (1.0f/(float)BTOT);
  }
}

extern "C" void kernel_launch(void* const* d_in, const int* in_sizes, int n_in,
                              void* d_out, int out_size, void* d_ws, size_t ws_size,
                              hipStream_t stream) {
  const float* x      = (const float*)d_in[0];
  const float* coords = (const float*)d_in[1];
  const float* wt     = (const float*)d_in[2];
  float* out    = (float*)d_out;
  float* attsum = (float*)d_ws;

  hipMemsetAsync(attsum, 0, NNODE*sizeof(float), stream);
  meso_main<<<BTOT/BPW, 256, 0, stream>>>(x, wt, out, attsum);
  meso_coor<<<1, 64, 0, stream>>>(attsum, coords, out + FEAT_OUT);
}

// Round 5
// 137.146 us; speedup vs baseline: 1.9434x; 1.2157x over previous
//
#include <hip/hip_runtime.h>
#include <math.h>

#define BTOT   32768
#define NNODE  78
#define NEMB   30
#define NPROJ  10
#define NGR    7
#define ROW    (NNODE*NEMB)       // 2340 floats per batch
#define BPW    8                  // batches per WG (8 half-waves, 256 thr)
#define FEAT_OUT (BTOT*NGR*NEMB)

__constant__ int d_off[NGR] = {0,5,14,23,48,57,66};
__constant__ int d_len[NGR] = {5,9,9,25,9,9,12};

// ---- cross-lane helpers: DPP (VALU pipe) for xor1/2/4-ish/8-ish, ds_swizzle only for xor16 ----
template<int CTRL>
__device__ __forceinline__ float dpp_f(float x) {
  return __int_as_float(__builtin_amdgcn_update_dpp(0, __float_as_int(x), CTRL, 0xF, 0xF, true));
}
__device__ __forceinline__ float swz16(float x) {  // exchange lanes 0-15 <-> 16-31 within each half-wave
  return __int_as_float(__builtin_amdgcn_ds_swizzle(__float_as_int(x), 0x401F));
}
// all-lanes sum within each 32-lane half (quad_perm xor1, xor2, half-mirror, mirror, swizzle xor16)
__device__ __forceinline__ float hsum32(float x) {
  x += dpp_f<0xB1>(x);    // quad_perm [1,0,3,2]  (xor 1)
  x += dpp_f<0x4E>(x);    // quad_perm [2,3,0,1]  (xor 2)
  x += dpp_f<0x141>(x);   // row_half_mirror: pairs the uniform 4-groups
  x += dpp_f<0x140>(x);   // row_mirror: pairs the uniform 8-groups
  x += swz16(x);          // combine 16-halves
  return x;
}

// One 32-lane group = one (batch, graph). Lane = embedding dim e. All static indices.
template<int OFF, int LEN, int G>
__device__ __forceinline__ void process_graph(
    const float* __restrict__ xrow, const float (&Wr)[NPROJ],
    float* __restrict__ arow, float* __restrict__ outb,
    int lane31, bool evalid, int e)
{
  // stream sub-block (x read once from HBM; lanes 30,31 clamp to e=29, neutralized via Wr=0)
  float xr[LEN];
  float xsum = 0.f;
#pragma unroll
  for (int j = 0; j < LEN; ++j) {
    xr[j] = xrow[(OFF + j) * NEMB + e];
    xsum += xr[j];
  }
  // t[h] = sum_e W[e,h] * xsum[e]   (10 butterflies; Wr zero in lanes>=30 kills clamp garbage)
  float t[NPROJ];
#pragma unroll
  for (int h = 0; h < NPROJ; ++h) t[h] = hsum32(Wr[h] * xsum);
  // u[e] = sum_h W[e,h] t[h]   (per-lane, no cross-lane; u=0 in lanes>=30)
  float u = 0.f;
#pragma unroll
  for (int h = 0; h < NPROJ; ++h) u = fmaf(Wr[h], t[h], u);
  // logits: butterfly allreduce -> every lane holds every logit (garbage lanes contribute 0)
  float lg[LEN];
#pragma unroll
  for (int j = 0; j < LEN; ++j) lg[j] = hsum32(xr[j] * u);
  // softmax fully per-lane (values uniform across lanes)
  float m = lg[0];
#pragma unroll
  for (int j = 1; j < LEN; ++j) m = fmaxf(m, lg[j]);
  float s = 0.f;
#pragma unroll
  for (int j = 0; j < LEN; ++j) { lg[j] = __expf(lg[j] - m); s += lg[j]; }
  float inv = 1.f / s;
  // feat[e] = sum_j att[j]*x[j,e] : per-lane fma; park own att for the cross-batch sum
  float f = 0.f, myatt = 0.f;
#pragma unroll
  for (int j = 0; j < LEN; ++j) {
    float a = lg[j] * inv;
    f = fmaf(a, xr[j], f);
    if (lane31 == j) myatt = a;
  }
  if (evalid) outb[G * NEMB + e] = f;            // 120B contiguous store
  if (lane31 < LEN) arow[OFF + lane31] = myatt;  // 1 conflict-free ds_write
}

__global__ __launch_bounds__(256) void meso_main(
    const float* __restrict__ x, const float* __restrict__ wt,
    float* __restrict__ out, float* __restrict__ attsum)
{
  __shared__ float att_all[BPW][NNODE];   // 2.4 KB — only LDS in the kernel

  const int tid    = threadIdx.x;
  const int half   = tid >> 5;
  const int lane31 = tid & 31;
  const bool evalid = lane31 < NEMB;
  const int e = evalid ? lane31 : (NEMB - 1);

  // lane's row of W (10 VGPRs); zero in lanes 30,31
  float Wr[NPROJ];
#pragma unroll
  for (int h = 0; h < NPROJ; ++h) Wr[h] = evalid ? wt[e * NPROJ + h] : 0.f;

  const long long b = (long long)blockIdx.x * BPW + half;
  const float* xrow = x + b * ROW;
  float* outb = out + b * (NGR * NEMB);
  float* arow = att_all[half];

  process_graph< 0, 5,0>(xrow, Wr, arow, outb, lane31, evalid, e);
  process_graph< 5, 9,1>(xrow, Wr, arow, outb, lane31, evalid, e);
  process_graph<14, 9,2>(xrow, Wr, arow, outb, lane31, evalid, e);
  process_graph<23,25,3>(xrow, Wr, arow, outb, lane31, evalid, e);
  process_graph<48, 9,4>(xrow, Wr, arow, outb, lane31, evalid, e);
  process_graph<57, 9,5>(xrow, Wr, arow, outb, lane31, evalid, e);
  process_graph<66,12,6>(xrow, Wr, arow, outb, lane31, evalid, e);

  __syncthreads();
  if (tid < NNODE) {
    float s = 0.f;
#pragma unroll
    for (int h = 0; h < BPW; ++h) s += att_all[h][tid];
    atomicAdd(&attsum[tid], s);
  }
}

__global__ void meso_coor(const float* __restrict__ attsum,
                          const float* __restrict__ coords,
                          float* __restrict__ out_coor)
{
  int t = threadIdx.x;
  if (t < NGR*3) {
    int g = t / 3, k = t % 3;
    int off = d_off[g], len = d_len[g];
    float s = 0.f;
    for (int j = 0; j < len; ++j) s += attsum[off+j] * coords[(off+j)*3 + k];
    out_coor[t] = s * (1.0f/(float)BTOT);
  }
}

extern "C" void kernel_launch(void* const* d_in, const int* in_sizes, int n_in,
                              void* d_out, int out_size, void* d_ws, size_t ws_size,
                              hipStream_t stream) {
  const float* x      = (const float*)d_in[0];
  const float* coords = (const float*)d_in[1];
  const float* wt     = (const float*)d_in[2];
  float* out    = (float*)d_out;
  float* attsum = (float*)d_ws;

  hipMemsetAsync(attsum, 0, NNODE*sizeof(float), stream);
  meso_main<<<BTOT/BPW, 256, 0, stream>>>(x, wt, out, attsum);
  meso_coor<<<1, 64, 0, stream>>>(attsum, coords, out + FEAT_OUT);
}